// Round 11
// baseline (210.005 us; speedup 1.0000x reference)
//
#include <hip/hip_runtime.h>
#include <hip/hip_bf16.h>

// Problem dims (fixed by reference)
#define B_SZ 4096
#define F_SZ 1024
#define P_SZ 64
#define H1D  256
#define H2D  128

typedef __attribute__((ext_vector_type(8)))  short  short8;    // 8 bf16 (4 VGPR) MFMA operand
typedef __attribute__((ext_vector_type(4)))  float  floatx4;   // 16x16 MFMA accumulator
typedef __attribute__((ext_vector_type(16))) float  floatx16;  // 32x32 MFMA accumulator
typedef __attribute__((ext_vector_type(2)))  float  float2v;
typedef __attribute__((ext_vector_type(4)))  float  float4v;

typedef __attribute__((address_space(1))) const void* gas_t;
typedef __attribute__((address_space(3))) void*       las_t;

__device__ __forceinline__ short bfbits(float f) {
  __bf16 h = (__bf16)f;            // RNE, v_cvt_pk_bf16_f32
  return __builtin_bit_cast(short, h);
}

__device__ __forceinline__ void gll16(const void* g, void* l) {
  __builtin_amdgcn_global_load_lds((gas_t)g, (las_t)l, 16, 0, 0);
}

// ---------------- ws layout (bf16, fragment-major) ----------------
#define WS_A_OFF   0
#define WS_W1_OFF  8388608UL
#define WS_W2_OFF  41943040UL
#define WS_NEEDED  46137344UL

__global__ __launch_bounds__(256) void prep_A(const float* __restrict__ feat,
                                              short8* __restrict__ outv) {
  const int c = blockIdx.x * 256 + threadIdx.x;   // 524288 chunks
  const int row = c & 15, kg = (c >> 4) & 3, f = (c >> 6) & 7, kt = (c >> 9) & 31, mt = c >> 14;
  const float* src = feat + (size_t)(mt * 128 + f * 16 + row) * F_SZ + kt * 32 + kg * 8;
  float4v v0 = *(const float4v*)src;
  float4v v1 = *(const float4v*)(src + 4);
  short8 o;
  #pragma unroll
  for (int j = 0; j < 4; ++j) { o[j] = bfbits(v0[j]); o[4 + j] = bfbits(v1[j]); }
  outv[c] = o;
}

__global__ __launch_bounds__(256) void prep_W1(const float* __restrict__ W1,
                                               short8* __restrict__ outv) {
  const int c = blockIdx.x * 256 + threadIdx.x;   // 2097152 chunks
  const int nr = c & 15, kg = (c >> 4) & 3, nf = (c >> 6) & 15, kt = (c >> 10) & 31, p = c >> 15;
  const float* src = W1 + ((size_t)p * F_SZ + kt * 32 + kg * 8) * H1D + nf * 16 + nr;
  short8 o;
  #pragma unroll
  for (int j = 0; j < 8; ++j) o[j] = bfbits(src[(size_t)j * H1D]);
  outv[c] = o;
}

__global__ __launch_bounds__(256) void prep_W2(const float* __restrict__ W2,
                                               short8* __restrict__ outv) {
  const int c = blockIdx.x * 256 + threadIdx.x;   // 262144 chunks
  const int qr = c & 15, kgl = (c >> 4) & 3, ks = (c >> 6) & 1, qf = (c >> 7) & 7,
            kc = (c >> 10) & 3, p = c >> 12;
  const float* src = W2 + ((size_t)p * H1D + kc * 64 + ks * 32 + kgl * 8) * H2D + qf * 16 + qr;
  short8 o;
  #pragma unroll
  for (int j = 0; j < 8; ++j) o[j] = bfbits(src[(size_t)j * H2D]);
  outv[c] = o;
}

// ---------------- main fused kernel: persistent block, 32x32x16 MFMA in L1 ----------------
// Grid 256 = 1 block/CU. Block owns one p, 4 m-tiles. 8 waves (2M x 4N), wave tile 128x64
// decomposed as 4 m-blocks x 2 n-blocks of 32x32 (MFMA 32x32x16, 2 per block per BK=32).
// LDS map (163840 bytes): identical to v10.
//   L1 bufs  [0, 98304): 3 x 32KB { A c0 8K | A c1 8K | B 16K }
//   W2       [98304, 163840): 64KB, staged once (j==0), resident
//   bufH     overlay [32768, 98304): one k-parity half of h1, 16x16-A-frag-major
//   partials overlay [32768, 36864)
// 32x32x16 fragment addressing reuses the SAME slot layout:
//   A frag (mb,kk): lane l reads slot (mb*2+((l&31)>>4))*64 + (kk*2+(l>>5))*16 + (l&15)
//   B frag (nb,kk): slot (wn*4+nb*2+((l&31)>>4))*64 + (kk*2+(l>>5))*16 + (l&15)
// C/D 32x32 mapping (m74/m101): col = lane&31, row = (reg&3)+8*(reg>>2)+4*(lane>>5).
#define BAR()   __builtin_amdgcn_s_barrier()
#define VM4()   asm volatile("s_waitcnt vmcnt(4)" ::: "memory")
#define VM0()   asm volatile("s_waitcnt vmcnt(0)" ::: "memory")

__global__ __launch_bounds__(512, 2)
void fused_mlp_v11(const char* __restrict__ ws,
                   const float* __restrict__ b1,
                   const float* __restrict__ b2,
                   const float* __restrict__ W3,
                   const float* __restrict__ b3,
                   float* __restrict__ out) {
  __shared__ __align__(16) char sm[163840];

  const int tid  = threadIdx.x;
  const int lane = tid & 63;
  const int wid  = tid >> 6;
  const int wm   = wid >> 2;   // 0..1 : m-half (128 rows)
  const int wn   = wid & 3;    // 0..3 : n-quarter (64 cols of H1)

  const int bid = blockIdx.x;
  const int wg  = (bid & 7) * 32 + (bid >> 3);    // XCD-chunked, bijective (256%8==0)
  const int p   = wg >> 2;                        // 4 blocks share p (same XCD -> W1 L2-hot)
  const int mq  = wg & 3;                         // m-tile quarter: mt = mq*4 + j

  const char* W1pre = ws + WS_W1_OFF + (size_t)p * 524288;   // per-kt 16KB
  const char* W2pre = ws + WS_W2_OFF + (size_t)p * 65536;    // 64KB

  const int c  = lane & 15;
  const int hi = lane >> 4;
  // 32x32-fragment lane offset within a 2-fragment-block group (see header)
  const int laneOff = ((lane & 31) >> 4) * 1024 + (lane >> 5) * 256 + (lane & 15) * 16;

  auto stage = [&](const char* Apre, int ib, int kt) {   // 4 x gll16, 32KB/tile
    char* base = sm + ib * 32768;
    gll16(Apre + (size_t)kt * 8192 + tid * 16,          base + wid * 1024);
    gll16(Apre + 262144 + (size_t)kt * 8192 + tid * 16, base + 8192 + wid * 1024);
    const char* gb = W1pre + (size_t)kt * 16384 + tid * 16;
    gll16(gb,        base + 16384 + wid * 1024);
    gll16(gb + 8192, base + 24576 + wid * 1024);
  };

  for (int j = 0; j < 4; ++j) {
    const int mt = mq * 4 + j;
    const int m0 = mt * 256;
    const char* Apre  = ws + WS_A_OFF + (size_t)(2 * mt) * 262144;
    const char* ApreN = Apre + 524288;

    floatx16 acc32[4][2];
    #pragma unroll
    for (int mb = 0; mb < 4; ++mb)
      #pragma unroll
      for (int nb = 0; nb < 2; ++nb)
        acc32[mb][nb] = (floatx16)0.0f;

    // ---- prologue ----
    if (j == 0) stage(Apre, 0, 0);
    stage(Apre, 1, 1);
    VM4();
    BAR();

    // ---- Layer 1: K = 1024, BK = 32, 3-deep rotation, counted vmcnt(4) ----
    int ibr = 0;
    for (int t = 0; t < 32; ++t) {
      const char* rb = sm + ibr * 32768;
      short8 af[4][2], bf[2][2];
      #pragma unroll
      for (int mb = 0; mb < 4; ++mb)
        #pragma unroll
        for (int kk = 0; kk < 2; ++kk)
          af[mb][kk] = *(const short8*)(rb + wm * 8192 + mb * 2048 + kk * 512 + laneOff);
      #pragma unroll
      for (int nb = 0; nb < 2; ++nb)
        #pragma unroll
        for (int kk = 0; kk < 2; ++kk)
          bf[nb][kk] = *(const short8*)(rb + 16384 + wn * 4096 + nb * 2048 + kk * 512 + laneOff);

      const int ibs = (ibr == 0) ? 2 : ibr - 1;
      if (t < 30) {
        stage(Apre, ibs, t + 2);
      } else if (t == 30) {
        if (j == 0) {
          gll16(W2pre + 0 * 8192 + tid * 16, sm + 98304 + 0 * 8192 + wid * 1024);
          gll16(W2pre + 1 * 8192 + tid * 16, sm + 98304 + 1 * 8192 + wid * 1024);
          gll16(W2pre + 2 * 8192 + tid * 16, sm + 98304 + 2 * 8192 + wid * 1024);
          gll16(W2pre + 3 * 8192 + tid * 16, sm + 98304 + 3 * 8192 + wid * 1024);
        }
      } else {          // t == 31: buf0 dead -> prefetch next mt's tile 0
        if (j == 0) {
          gll16(W2pre + 4 * 8192 + tid * 16, sm + 98304 + 4 * 8192 + wid * 1024);
          gll16(W2pre + 5 * 8192 + tid * 16, sm + 98304 + 5 * 8192 + wid * 1024);
          gll16(W2pre + 6 * 8192 + tid * 16, sm + 98304 + 6 * 8192 + wid * 1024);
          gll16(W2pre + 7 * 8192 + tid * 16, sm + 98304 + 7 * 8192 + wid * 1024);
        }
        if (j < 3) stage(ApreN, 0, 0);
      }

      __builtin_amdgcn_s_setprio(1);
      #pragma unroll
      for (int kk = 0; kk < 2; ++kk)
        #pragma unroll
        for (int mb = 0; mb < 4; ++mb)
          #pragma unroll
          for (int nb = 0; nb < 2; ++nb)
            acc32[mb][nb] = __builtin_amdgcn_mfma_f32_32x32x16_bf16(
                af[mb][kk], bf[nb][kk], acc32[mb][nb], 0, 0, 0);
      __builtin_amdgcn_s_setprio(0);

      if (t < 31) {
        if (t < 30 || j == 0) VM4();
        else VM0();
        BAR();
      }
      ibr = (ibr == 2) ? 0 : ibr + 1;
    }
    __syncthreads();   // full drain; bufs 1/2 reusable as bufH

    // ---- Phase 2: layer 2 in two k-parity halves; bufH at [32768,98304) ----
    // nb of acc32 IS the parity half: q = wn*64 + nb*32 + (lane&31).
    float b1v2[2];
    #pragma unroll
    for (int h = 0; h < 2; ++h)
      b1v2[h] = b1[p * H1D + wn * 64 + h * 32 + (lane & 31)];

    floatx4 acc2[8][2];
    #pragma unroll
    for (int mi = 0; mi < 8; ++mi)
      #pragma unroll
      for (int qi = 0; qi < 2; ++qi)
        acc2[mi][qi] = (floatx4)0.0f;

    const int kg2j = ((lane & 31) >> 3) * 256 + (lane & 7) * 2;   // k-group + j byte offset

    #pragma unroll
    for (int h = 0; h < 2; ++h) {
      // scatter relu(h1+b1) from 32x32 C/D into 16x16 A-frag-major bufH (slot s = wn)
      #pragma unroll
      for (int mb = 0; mb < 4; ++mb) {
        #pragma unroll
        for (int reg = 0; reg < 16; ++reg) {
          const int row16 = (reg & 3) + 8 * ((reg >> 2) & 1) + 4 * (lane >> 5);
          const int fblk  = mb * 2 + (reg >> 3);
          const int F     = wn * 16 + wm * 8 + fblk;
          const float v   = fmaxf(acc32[mb][h][reg] + b1v2[h], 0.0f);
          *(short*)(sm + 32768 + F * 1024 + kg2j + row16 * 16) = bfbits(v);
        }
      }
      __syncthreads();   // scatter visible

      #pragma unroll
      for (int s = 0; s < 4; ++s) {
        short8 hf[8], wf[2];
        #pragma unroll
        for (int mi = 0; mi < 8; ++mi)
          hf[mi] = *(const short8*)(sm + 32768 + (s * 16 + wm * 8 + mi) * 1024 + lane * 16);
        #pragma unroll
        for (int qi = 0; qi < 2; ++qi)
          wf[qi] = *(const short8*)(sm + 98304 + s * 16384 + (wn * 2 + qi) * 2048
                                    + h * 1024 + lane * 16);
        #pragma unroll
        for (int mi = 0; mi < 8; ++mi)
          #pragma unroll
          for (int qi = 0; qi < 2; ++qi)
            acc2[mi][qi] = __builtin_amdgcn_mfma_f32_16x16x32_bf16(hf[mi], wf[qi], acc2[mi][qi], 0, 0, 0);
      }
      __syncthreads();   // bufH reads done before next half's scatter
    }

    // ---- Layer 3: logits = relu(h2+b2) . W3 + b3 ; sigmoid; transposed store ----
    float lsum[8][4];
    #pragma unroll
    for (int mi = 0; mi < 8; ++mi)
      #pragma unroll
      for (int r = 0; r < 4; ++r) lsum[mi][r] = 0.0f;

    #pragma unroll
    for (int qi = 0; qi < 2; ++qi) {
      const int q = wn * 32 + qi * 16 + c;
      const float b2v = b2[p * H2D + q];
      const float w3v = W3[p * H2D + q];
      #pragma unroll
      for (int mi = 0; mi < 8; ++mi)
        #pragma unroll
        for (int r = 0; r < 4; ++r) {
          const float h2v = fmaxf(acc2[mi][qi][r] + b2v, 0.0f);
          lsum[mi][r] += h2v * w3v;
        }
    }
    #pragma unroll
    for (int mask = 1; mask <= 8; mask <<= 1)
      #pragma unroll
      for (int mi = 0; mi < 8; ++mi)
        #pragma unroll
        for (int r = 0; r < 4; ++r)
          lsum[mi][r] += __shfl_xor(lsum[mi][r], mask, 64);

    float* part = (float*)(sm + 32768);   // dead bufH region; buf0 untouched
    if (c == 0) {
      #pragma unroll
      for (int mi = 0; mi < 8; ++mi)
        #pragma unroll
        for (int r = 0; r < 4; ++r)
          part[wn * 256 + wm * 128 + mi * 16 + hi * 4 + r] = lsum[mi][r];
    }
    __syncthreads();
    if (tid < 256) {
      const float x = part[tid] + part[256 + tid] + part[512 + tid] + part[768 + tid] + b3[p];
      const float s = 1.0f / (1.0f + __expf(-x));
      out[(size_t)(m0 + tid) * P_SZ + p] = s;
    }
    __syncthreads();   // partials reads done before next mt reuses buf1
  }
}

// ---------------- fallback (R0 kernel, f32 reg-staged) — used when ws too small ----------------
__global__ __launch_bounds__(512, 2)
void fused_mlp_kernel(const float* __restrict__ feat,
                      const float* __restrict__ W1,
                      const float* __restrict__ b1,
                      const float* __restrict__ W2,
                      const float* __restrict__ b2,
                      const float* __restrict__ W3,
                      const float* __restrict__ b3,
                      float* __restrict__ out) {
  __shared__ __align__(16) char sm[49152];
  const int tid  = threadIdx.x;
  const int lane = tid & 63;
  const int wid  = tid >> 6;
  const int wm   = wid >> 2;
  const int wn   = wid & 3;
  const int bid = blockIdx.x;
  const int wg  = (bid & 7) * 256 + (bid >> 3);
  const int p   = wg >> 5;
  const int mt  = wg & 31;
  const int m0  = mt * 128;

  const float* featm = feat + (size_t)m0 * F_SZ;
  const float* W1p   = W1 + (size_t)p * F_SZ * H1D;
  const float* b1p   = b1 + p * H1D;
  const float* W2p   = W2 + (size_t)p * H1D * H2D;
  const float* b2p   = b2 + p * H2D;
  const float* W3p   = W3 + p * H2D;

  const int a_m  = tid >> 2;
  const int a_kg = tid & 3;
  const int b_n2 = tid & 127;
  const int b_kq = tid >> 7;

  float a_reg[8];
  float b_reg[16];
  floatx4 acc[4][4];
  #pragma unroll
  for (int i = 0; i < 4; ++i)
    #pragma unroll
    for (int j = 0; j < 4; ++j)
      acc[i][j] = (floatx4)0.0f;

  auto stage_load = [&](int k0) {
    const float* pa = featm + a_m * F_SZ + k0 + a_kg * 8;
    *(float4v*)(&a_reg[0]) = *(const float4v*)(pa);
    *(float4v*)(&a_reg[4]) = *(const float4v*)(pa + 4);
    #pragma unroll
    for (int i = 0; i < 8; ++i) {
      const float* pb = W1p + (size_t)(k0 + b_kq * 8 + i) * H1D + b_n2 * 2;
      *(float2v*)(&b_reg[2 * i]) = *(const float2v*)(pb);
    }
  };
  auto stage_write = [&](int cur) {
    short8 av;
    #pragma unroll
    for (int i = 0; i < 8; ++i) av[i] = bfbits(a_reg[i]);
    const int aslot = (a_m >> 4) * 64 + (a_m & 15) + a_kg * 16;
    *(short8*)(sm + cur * 8192 + aslot * 16) = av;
    #pragma unroll
    for (int dn = 0; dn < 2; ++dn) {
      short8 bv;
      #pragma unroll
      for (int i = 0; i < 8; ++i) bv[i] = bfbits(b_reg[2 * i + dn]);
      const int n = b_n2 * 2 + dn;
      const int bslot = (n >> 4) * 64 + (n & 15) + b_kq * 16;
      *(short8*)(sm + 16384 + cur * 16384 + bslot * 16) = bv;
    }
  };
  auto compute = [&](int cur) {
    short8 af[4], bfr[4];
    #pragma unroll
    for (int mi = 0; mi < 4; ++mi)
      af[mi] = *(const short8*)(sm + cur * 8192 + ((wm * 4 + mi) * 64 + lane) * 16);
    #pragma unroll
    for (int ni = 0; ni < 4; ++ni)
      bfr[ni] = *(const short8*)(sm + 16384 + cur * 16384 + ((wn * 4 + ni) * 64 + lane) * 16);
    #pragma unroll
    for (int mi = 0; mi < 4; ++mi)
      #pragma unroll
      for (int ni = 0; ni < 4; ++ni)
        acc[mi][ni] = __builtin_amdgcn_mfma_f32_16x16x32_bf16(af[mi], bfr[ni], acc[mi][ni], 0, 0, 0);
  };

  stage_load(0);
  stage_write(0);
  __syncthreads();
  int cur = 0;
  for (int t = 0; t < 32; ++t) {
    if (t + 1 < 32) stage_load((t + 1) * 32);
    compute(cur);
    if (t + 1 < 32) stage_write(cur ^ 1);
    __syncthreads();
    cur ^= 1;
  }

  floatx4 acc2[4][2];
  #pragma unroll
  for (int mi = 0; mi < 4; ++mi)
    #pragma unroll
    for (int qi = 0; qi < 2; ++qi)
      acc2[mi][qi] = (floatx4)0.0f;

  float b1v[4];
  #pragma unroll
  for (int ni = 0; ni < 4; ++ni)
    b1v[ni] = b1p[wn * 64 + ni * 16 + (lane & 15)];

  const int w2_q2 = tid & 63;
  const int w2_kq = tid >> 6;

  for (int kc = 0; kc < 4; ++kc) {
    const int kbase = kc * 64;
    float w2reg[16];
    #pragma unroll
    for (int i = 0; i < 8; ++i) {
      const float* pw = W2p + (size_t)(kbase + w2_kq * 8 + i) * H2D + w2_q2 * 2;
      *(float2v*)(&w2reg[2 * i]) = *(const float2v*)(pw);
    }
    #pragma unroll
    for (int dq = 0; dq < 2; ++dq) {
      short8 wv;
      #pragma unroll
      for (int i = 0; i < 8; ++i) wv[i] = bfbits(w2reg[2 * i + dq]);
      const int q = w2_q2 * 2 + dq;
      const int slot = ((q >> 4) * 2 + (w2_kq >> 2)) * 64 + (w2_kq & 3) * 16 + (q & 15);
      *(short8*)(sm + 16384 + slot * 16) = wv;
    }
    if (wn == kc) {
      #pragma unroll
      for (int mi = 0; mi < 4; ++mi) {
        #pragma unroll
        for (int ni = 0; ni < 4; ++ni) {
          const int kl = ni * 16 + (lane & 15);
          const int base = (((wm * 4 + mi) * 2 + (kl >> 5)) * 64 + ((kl >> 3) & 3) * 16) * 16
                           + (kl & 7) * 2;
          #pragma unroll
          for (int r = 0; r < 4; ++r) {
            float v = fmaxf(acc[mi][ni][r] + b1v[ni], 0.0f);
            const int row = (lane >> 4) * 4 + r;
            *(short*)(sm + base + row * 16) = bfbits(v);
          }
        }
      }
    }
    __syncthreads();
    #pragma unroll
    for (int ks = 0; ks < 2; ++ks) {
      short8 hf[4], wf[2];
      #pragma unroll
      for (int mi = 0; mi < 4; ++mi)
        hf[mi] = *(const short8*)(sm + (((wm * 4 + mi) * 2 + ks) * 64 + lane) * 16);
      #pragma unroll
      for (int qi = 0; qi < 2; ++qi)
        wf[qi] = *(const short8*)(sm + 16384 + (((wn * 2 + qi) * 2 + ks) * 64 + lane) * 16);
      #pragma unroll
      for (int mi = 0; mi < 4; ++mi)
        #pragma unroll
        for (int qi = 0; qi < 2; ++qi)
          acc2[mi][qi] = __builtin_amdgcn_mfma_f32_16x16x32_bf16(hf[mi], wf[qi], acc2[mi][qi], 0, 0, 0);
    }
    __syncthreads();
  }

  float lsum[4][4];
  #pragma unroll
  for (int mi = 0; mi < 4; ++mi)
    #pragma unroll
    for (int r = 0; r < 4; ++r) lsum[mi][r] = 0.0f;

  #pragma unroll
  for (int qi = 0; qi < 2; ++qi) {
    const int q = wn * 32 + qi * 16 + (lane & 15);
    const float b2v = b2p[q];
    const float w3v = W3p[q];
    #pragma unroll
    for (int mi = 0; mi < 4; ++mi)
      #pragma unroll
      for (int r = 0; r < 4; ++r) {
        const float h = fmaxf(acc2[mi][qi][r] + b2v, 0.0f);
        lsum[mi][r] += h * w3v;
      }
  }
  #pragma unroll
  for (int mask = 1; mask <= 8; mask <<= 1)
    #pragma unroll
    for (int mi = 0; mi < 4; ++mi)
      #pragma unroll
      for (int r = 0; r < 4; ++r)
        lsum[mi][r] += __shfl_xor(lsum[mi][r], mask, 64);

  float* part = (float*)(sm + 32768);
  if ((lane & 15) == 0) {
    const int g = lane >> 4;
    #pragma unroll
    for (int mi = 0; mi < 4; ++mi)
      #pragma unroll
      for (int r = 0; r < 4; ++r)
        part[wn * 128 + wm * 64 + mi * 16 + g * 4 + r] = lsum[mi][r];
  }
  __syncthreads();
  if (tid < 128) {
    const float x = part[tid] + part[128 + tid] + part[256 + tid] + part[384 + tid] + b3[p];
    const float s = 1.0f / (1.0f + __expf(-x));
    out[(size_t)(m0 + tid) * P_SZ + p] = s;
  }
}

extern "C" void kernel_launch(void* const* d_in, const int* in_sizes, int n_in,
                              void* d_out, int out_size, void* d_ws, size_t ws_size,
                              hipStream_t stream) {
  (void)in_sizes; (void)n_in; (void)out_size;
  const float* feat = (const float*)d_in[0];
  const float* W1   = (const float*)d_in[1];
  const float* b1   = (const float*)d_in[2];
  const float* W2   = (const float*)d_in[3];
  const float* b2   = (const float*)d_in[4];
  const float* W3   = (const float*)d_in[5];
  const float* b3   = (const float*)d_in[6];
  float* out = (float*)d_out;

  if (ws_size >= WS_NEEDED) {
    char* ws = (char*)d_ws;
    hipLaunchKernelGGL(prep_A,  dim3(2048), dim3(256), 0, stream, feat, (short8*)(ws + WS_A_OFF));
    hipLaunchKernelGGL(prep_W1, dim3(8192), dim3(256), 0, stream, W1,   (short8*)(ws + WS_W1_OFF));
    hipLaunchKernelGGL(prep_W2, dim3(1024), dim3(256), 0, stream, W2,   (short8*)(ws + WS_W2_OFF));
    hipLaunchKernelGGL(fused_mlp_v11, dim3(256), dim3(512), 0, stream,
                       (const char*)ws, b1, b2, W3, b3, out);
  } else {
    hipLaunchKernelGGL(fused_mlp_kernel, dim3(2048), dim3(512), 0, stream,
                       feat, W1, b1, W2, b2, W3, b3, out);
  }
}

// Round 12
// 191.824 us; speedup vs baseline: 1.0948x; 1.0948x over previous
//
#include <hip/hip_runtime.h>
#include <hip/hip_bf16.h>

// Problem dims (fixed by reference)
#define B_SZ 4096
#define F_SZ 1024
#define P_SZ 64
#define H1D  256
#define H2D  128

typedef __attribute__((ext_vector_type(8)))  short  short8;    // 8 bf16 (4 VGPR) MFMA operand
typedef __attribute__((ext_vector_type(4)))  float  floatx4;   // 16x16 MFMA accumulator
typedef __attribute__((ext_vector_type(16))) float  floatx16;  // 32x32 MFMA accumulator
typedef __attribute__((ext_vector_type(2)))  float  float2v;
typedef __attribute__((ext_vector_type(4)))  float  float4v;

typedef __attribute__((address_space(1))) const void* gas_t;
typedef __attribute__((address_space(3))) void*       las_t;

__device__ __forceinline__ short bfbits(float f) {
  __bf16 h = (__bf16)f;            // RNE, v_cvt_pk_bf16_f32
  return __builtin_bit_cast(short, h);
}

__device__ __forceinline__ void gll16(const void* g, void* l) {
  __builtin_amdgcn_global_load_lds((gas_t)g, (las_t)l, 16, 0, 0);
}

// ---------------- ws layout (bf16, 32x32-fragment-major for L1; W2 16x16 as before) ----
// A_pre  [0,        8388608): feat -> [mt128(32)][kt(32)][mb(4)][kk(2)][lane(64)][8]
//        value = feat[mt128*128 + mb*32 + (lane&31)][kt*32 + kk*16 + (lane>>5)*8 + j]
// W1_pre [8388608, 41943040): W1   -> [p(64)][kt(32)][nf(8)][kk(2)][lane(64)][8]
//        value = W1[p][kt*32 + kk*16 + (lane>>5)*8 + j][nf*32 + (lane&31)]
// W2_pre [41943040,46137344): W2   -> [p(64)][kc(4)][slot(1024)][8]  (16x16 frag, unchanged)
#define WS_A_OFF   0
#define WS_W1_OFF  8388608UL
#define WS_W2_OFF  41943040UL
#define WS_NEEDED  46137344UL

__global__ __launch_bounds__(256) void prep_A(const float* __restrict__ feat,
                                              short8* __restrict__ outv) {
  const int c = blockIdx.x * 256 + threadIdx.x;   // 524288 chunks
  const int lane = c & 63, kk = (c >> 6) & 1, mb = (c >> 7) & 3,
            kt = (c >> 9) & 31, mt = c >> 14;
  const float* src = feat + (size_t)(mt * 128 + mb * 32 + (lane & 31)) * F_SZ
                     + kt * 32 + kk * 16 + (lane >> 5) * 8;
  float4v v0 = *(const float4v*)src;
  float4v v1 = *(const float4v*)(src + 4);
  short8 o;
  #pragma unroll
  for (int j = 0; j < 4; ++j) { o[j] = bfbits(v0[j]); o[4 + j] = bfbits(v1[j]); }
  outv[c] = o;
}

__global__ __launch_bounds__(256) void prep_W1(const float* __restrict__ W1,
                                               short8* __restrict__ outv) {
  const int c = blockIdx.x * 256 + threadIdx.x;   // 2097152 chunks
  const int lane = c & 63, kk = (c >> 6) & 1, nf = (c >> 7) & 7,
            kt = (c >> 10) & 31, p = c >> 15;
  const float* src = W1 + ((size_t)p * F_SZ + kt * 32 + kk * 16 + (lane >> 5) * 8) * H1D
                     + nf * 32 + (lane & 31);
  short8 o;
  #pragma unroll
  for (int j = 0; j < 8; ++j) o[j] = bfbits(src[(size_t)j * H1D]);
  outv[c] = o;
}

__global__ __launch_bounds__(256) void prep_W2(const float* __restrict__ W2,
                                               short8* __restrict__ outv) {
  const int c = blockIdx.x * 256 + threadIdx.x;   // 262144 chunks
  const int qr = c & 15, kgl = (c >> 4) & 3, ks = (c >> 6) & 1, qf = (c >> 7) & 7,
            kc = (c >> 10) & 3, p = c >> 12;
  const float* src = W2 + ((size_t)p * H1D + kc * 64 + ks * 32 + kgl * 8) * H2D + qf * 16 + qr;
  short8 o;
  #pragma unroll
  for (int j = 0; j < 8; ++j) o[j] = bfbits(src[(size_t)j * H2D]);
  outv[c] = o;
}

// ---------------- main fused kernel: persistent block, 32x32x16 MFMA, lane-linear frags ----
// Grid 256 = 1 block/CU. Block owns one p, 4 m-tiles. 8 waves (2M x 4N), wave tile 128x64
// = 4 m-blocks x 2 n-blocks of 32x32; MFMA 32x32x16, 2 K-substeps (kk) per BK=32.
// LDS map (163840 bytes): identical to v10.
//   L1 bufs  [0, 98304): 3 x 32KB { A(frag-major 32x32) 16K | B(frag-major 32x32) 16K }
//   W2       [98304, 163840): 64KB, staged once (j==0), resident
//   bufH     overlay [32768, 98304): one k-parity half of h1, 16x16-A-frag-major
//   partials overlay [32768, 36864)
// All L1 ds_reads: frag*1024 + lane*16 (lane-linear, conflict-free — v10 pattern).
// C/D 32x32 (m74/m101): col = lane&31, row = (reg&3)+8*(reg>>2)+4*(lane>>5).
#define BAR()   __builtin_amdgcn_s_barrier()
#define VM4()   asm volatile("s_waitcnt vmcnt(4)" ::: "memory")
#define VM0()   asm volatile("s_waitcnt vmcnt(0)" ::: "memory")

__global__ __launch_bounds__(512, 2)
void fused_mlp_v12(const char* __restrict__ ws,
                   const float* __restrict__ b1,
                   const float* __restrict__ b2,
                   const float* __restrict__ W3,
                   const float* __restrict__ b3,
                   float* __restrict__ out) {
  __shared__ __align__(16) char sm[163840];

  const int tid  = threadIdx.x;
  const int lane = tid & 63;
  const int wid  = tid >> 6;
  const int wm   = wid >> 2;   // 0..1 : m-half (128 rows)
  const int wn   = wid & 3;    // 0..3 : n-quarter (64 cols of H1)

  const int bid = blockIdx.x;
  const int wg  = (bid & 7) * 32 + (bid >> 3);    // XCD-chunked, bijective (256%8==0)
  const int p   = wg >> 2;                        // 4 blocks share p (same XCD -> W1 L2-hot)
  const int mq  = wg & 3;                         // m-tile quarter: mt = mq*4 + j

  const char* W1pre = ws + WS_W1_OFF + (size_t)p * 524288;   // per-kt 16KB
  const char* W2pre = ws + WS_W2_OFF + (size_t)p * 65536;    // 64KB

  const int c  = lane & 15;
  const int hi = lane >> 4;

  auto stage = [&](const char* Apre, int ib, int kt) {   // 4 x gll16, 32KB/tile
    char* base = sm + ib * 32768;
    gll16(Apre + (size_t)kt * 8192 + tid * 16,          base + wid * 1024);
    gll16(Apre + 262144 + (size_t)kt * 8192 + tid * 16, base + 8192 + wid * 1024);
    const char* gb = W1pre + (size_t)kt * 16384 + tid * 16;
    gll16(gb,        base + 16384 + wid * 1024);
    gll16(gb + 8192, base + 24576 + wid * 1024);
  };

  for (int j = 0; j < 4; ++j) {
    const int mt = mq * 4 + j;
    const int m0 = mt * 256;
    const char* Apre  = ws + WS_A_OFF + (size_t)(2 * mt) * 262144;
    const char* ApreN = Apre + 524288;

    floatx16 acc32[4][2];
    #pragma unroll
    for (int mb = 0; mb < 4; ++mb)
      #pragma unroll
      for (int nb = 0; nb < 2; ++nb)
        acc32[mb][nb] = (floatx16)0.0f;

    // ---- prologue ----
    if (j == 0) stage(Apre, 0, 0);
    stage(Apre, 1, 1);
    VM4();
    BAR();

    // ---- Layer 1: K = 1024, BK = 32, 3-deep rotation, counted vmcnt(4) ----
    int ibr = 0;
    for (int t = 0; t < 32; ++t) {
      const char* rb = sm + ibr * 32768;
      short8 af[4][2], bf[2][2];
      // A frag (mb,kk): wm-half selects 8KB chunk; frag index = mb*2+kk; lane-linear
      #pragma unroll
      for (int mb = 0; mb < 4; ++mb)
        #pragma unroll
        for (int kk = 0; kk < 2; ++kk)
          af[mb][kk] = *(const short8*)(rb + wm * 8192 + (mb * 2 + kk) * 1024 + lane * 16);
      // B frag (nb,kk): nf = wn*2+nb; frag index = nf*2+kk; lane-linear
      #pragma unroll
      for (int nb = 0; nb < 2; ++nb)
        #pragma unroll
        for (int kk = 0; kk < 2; ++kk)
          bf[nb][kk] = *(const short8*)(rb + 16384 + ((wn * 2 + nb) * 2 + kk) * 1024 + lane * 16);

      const int ibs = (ibr == 0) ? 2 : ibr - 1;
      if (t < 30) {
        stage(Apre, ibs, t + 2);
      } else if (t == 30) {
        if (j == 0) {
          gll16(W2pre + 0 * 8192 + tid * 16, sm + 98304 + 0 * 8192 + wid * 1024);
          gll16(W2pre + 1 * 8192 + tid * 16, sm + 98304 + 1 * 8192 + wid * 1024);
          gll16(W2pre + 2 * 8192 + tid * 16, sm + 98304 + 2 * 8192 + wid * 1024);
          gll16(W2pre + 3 * 8192 + tid * 16, sm + 98304 + 3 * 8192 + wid * 1024);
        }
      } else {          // t == 31: buf0 dead -> prefetch next mt's tile 0
        if (j == 0) {
          gll16(W2pre + 4 * 8192 + tid * 16, sm + 98304 + 4 * 8192 + wid * 1024);
          gll16(W2pre + 5 * 8192 + tid * 16, sm + 98304 + 5 * 8192 + wid * 1024);
          gll16(W2pre + 6 * 8192 + tid * 16, sm + 98304 + 6 * 8192 + wid * 1024);
          gll16(W2pre + 7 * 8192 + tid * 16, sm + 98304 + 7 * 8192 + wid * 1024);
        }
        if (j < 3) stage(ApreN, 0, 0);
      }

      __builtin_amdgcn_s_setprio(1);
      #pragma unroll
      for (int kk = 0; kk < 2; ++kk)
        #pragma unroll
        for (int mb = 0; mb < 4; ++mb)
          #pragma unroll
          for (int nb = 0; nb < 2; ++nb)
            acc32[mb][nb] = __builtin_amdgcn_mfma_f32_32x32x16_bf16(
                af[mb][kk], bf[nb][kk], acc32[mb][nb], 0, 0, 0);
      __builtin_amdgcn_s_setprio(0);

      if (t < 31) {
        if (t < 30 || j == 0) VM4();
        else VM0();
        BAR();
      }
      ibr = (ibr == 2) ? 0 : ibr + 1;
    }
    __syncthreads();   // full drain; bufs 1/2 reusable as bufH

    // ---- Phase 2: layer 2 in two k-parity halves; bufH at [32768,98304) ----
    // nb of acc32 IS the parity half: q = wn*64 + nb*32 + (lane&31). (v11-verified scatter)
    float b1v2[2];
    #pragma unroll
    for (int h = 0; h < 2; ++h)
      b1v2[h] = b1[p * H1D + wn * 64 + h * 32 + (lane & 31)];

    floatx4 acc2[8][2];
    #pragma unroll
    for (int mi = 0; mi < 8; ++mi)
      #pragma unroll
      for (int qi = 0; qi < 2; ++qi)
        acc2[mi][qi] = (floatx4)0.0f;

    const int kg2j = ((lane & 31) >> 3) * 256 + (lane & 7) * 2;   // k-group + j byte offset

    #pragma unroll
    for (int h = 0; h < 2; ++h) {
      // scatter relu(h1+b1) from 32x32 C/D into 16x16 A-frag-major bufH (slot s = wn)
      #pragma unroll
      for (int mb = 0; mb < 4; ++mb) {
        #pragma unroll
        for (int reg = 0; reg < 16; ++reg) {
          const int row16 = (reg & 3) + 8 * ((reg >> 2) & 1) + 4 * (lane >> 5);
          const int fblk  = mb * 2 + (reg >> 3);
          const int F     = wn * 16 + wm * 8 + fblk;
          const float v   = fmaxf(acc32[mb][h][reg] + b1v2[h], 0.0f);
          *(short*)(sm + 32768 + F * 1024 + kg2j + row16 * 16) = bfbits(v);
        }
      }
      __syncthreads();   // scatter visible

      #pragma unroll
      for (int s = 0; s < 4; ++s) {
        short8 hf[8], wf[2];
        #pragma unroll
        for (int mi = 0; mi < 8; ++mi)
          hf[mi] = *(const short8*)(sm + 32768 + (s * 16 + wm * 8 + mi) * 1024 + lane * 16);
        #pragma unroll
        for (int qi = 0; qi < 2; ++qi)
          wf[qi] = *(const short8*)(sm + 98304 + s * 16384 + (wn * 2 + qi) * 2048
                                    + h * 1024 + lane * 16);
        #pragma unroll
        for (int mi = 0; mi < 8; ++mi)
          #pragma unroll
          for (int qi = 0; qi < 2; ++qi)
            acc2[mi][qi] = __builtin_amdgcn_mfma_f32_16x16x32_bf16(hf[mi], wf[qi], acc2[mi][qi], 0, 0, 0);
      }
      __syncthreads();   // bufH reads done before next half's scatter
    }

    // ---- Layer 3: logits = relu(h2+b2) . W3 + b3 ; sigmoid; transposed store ----
    float lsum[8][4];
    #pragma unroll
    for (int mi = 0; mi < 8; ++mi)
      #pragma unroll
      for (int r = 0; r < 4; ++r) lsum[mi][r] = 0.0f;

    #pragma unroll
    for (int qi = 0; qi < 2; ++qi) {
      const int q = wn * 32 + qi * 16 + c;
      const float b2v = b2[p * H2D + q];
      const float w3v = W3[p * H2D + q];
      #pragma unroll
      for (int mi = 0; mi < 8; ++mi)
        #pragma unroll
        for (int r = 0; r < 4; ++r) {
          const float h2v = fmaxf(acc2[mi][qi][r] + b2v, 0.0f);
          lsum[mi][r] += h2v * w3v;
        }
    }
    #pragma unroll
    for (int mask = 1; mask <= 8; mask <<= 1)
      #pragma unroll
      for (int mi = 0; mi < 8; ++mi)
        #pragma unroll
        for (int r = 0; r < 4; ++r)
          lsum[mi][r] += __shfl_xor(lsum[mi][r], mask, 64);

    float* part = (float*)(sm + 32768);   // dead bufH region; buf0 untouched
    if (c == 0) {
      #pragma unroll
      for (int mi = 0; mi < 8; ++mi)
        #pragma unroll
        for (int r = 0; r < 4; ++r)
          part[wn * 256 + wm * 128 + mi * 16 + hi * 4 + r] = lsum[mi][r];
    }
    __syncthreads();
    if (tid < 256) {
      const float x = part[tid] + part[256 + tid] + part[512 + tid] + part[768 + tid] + b3[p];
      const float s = 1.0f / (1.0f + __expf(-x));
      out[(size_t)(m0 + tid) * P_SZ + p] = s;
    }
    __syncthreads();   // partials reads done before next mt reuses buf1
  }
}

// ---------------- fallback (R0 kernel, f32 reg-staged) — used when ws too small ----------------
__global__ __launch_bounds__(512, 2)
void fused_mlp_kernel(const float* __restrict__ feat,
                      const float* __restrict__ W1,
                      const float* __restrict__ b1,
                      const float* __restrict__ W2,
                      const float* __restrict__ b2,
                      const float* __restrict__ W3,
                      const float* __restrict__ b3,
                      float* __restrict__ out) {
  __shared__ __align__(16) char sm[49152];
  const int tid  = threadIdx.x;
  const int lane = tid & 63;
  const int wid  = tid >> 6;
  const int wm   = wid >> 2;
  const int wn   = wid & 3;
  const int bid = blockIdx.x;
  const int wg  = (bid & 7) * 256 + (bid >> 3);
  const int p   = wg >> 5;
  const int mt  = wg & 31;
  const int m0  = mt * 128;

  const float* featm = feat + (size_t)m0 * F_SZ;
  const float* W1p   = W1 + (size_t)p * F_SZ * H1D;
  const float* b1p   = b1 + p * H1D;
  const float* W2p   = W2 + (size_t)p * H1D * H2D;
  const float* b2p   = b2 + p * H2D;
  const float* W3p   = W3 + p * H2D;

  const int a_m  = tid >> 2;
  const int a_kg = tid & 3;
  const int b_n2 = tid & 127;
  const int b_kq = tid >> 7;

  float a_reg[8];
  float b_reg[16];
  floatx4 acc[4][4];
  #pragma unroll
  for (int i = 0; i < 4; ++i)
    #pragma unroll
    for (int j = 0; j < 4; ++j)
      acc[i][j] = (floatx4)0.0f;

  auto stage_load = [&](int k0) {
    const float* pa = featm + a_m * F_SZ + k0 + a_kg * 8;
    *(float4v*)(&a_reg[0]) = *(const float4v*)(pa);
    *(float4v*)(&a_reg[4]) = *(const float4v*)(pa + 4);
    #pragma unroll
    for (int i = 0; i < 8; ++i) {
      const float* pb = W1p + (size_t)(k0 + b_kq * 8 + i) * H1D + b_n2 * 2;
      *(float2v*)(&b_reg[2 * i]) = *(const float2v*)(pb);
    }
  };
  auto stage_write = [&](int cur) {
    short8 av;
    #pragma unroll
    for (int i = 0; i < 8; ++i) av[i] = bfbits(a_reg[i]);
    const int aslot = (a_m >> 4) * 64 + (a_m & 15) + a_kg * 16;
    *(short8*)(sm + cur * 8192 + aslot * 16) = av;
    #pragma unroll
    for (int dn = 0; dn < 2; ++dn) {
      short8 bv;
      #pragma unroll
      for (int i = 0; i < 8; ++i) bv[i] = bfbits(b_reg[2 * i + dn]);
      const int n = b_n2 * 2 + dn;
      const int bslot = (n >> 4) * 64 + (n & 15) + b_kq * 16;
      *(short8*)(sm + 16384 + cur * 16384 + bslot * 16) = bv;
    }
  };
  auto compute = [&](int cur) {
    short8 af[4], bfr[4];
    #pragma unroll
    for (int mi = 0; mi < 4; ++mi)
      af[mi] = *(const short8*)(sm + cur * 8192 + ((wm * 4 + mi) * 64 + lane) * 16);
    #pragma unroll
    for (int ni = 0; ni < 4; ++ni)
      bfr[ni] = *(const short8*)(sm + 16384 + cur * 16384 + ((wn * 4 + ni) * 64 + lane) * 16);
    #pragma unroll
    for (int mi = 0; mi < 4; ++mi)
      #pragma unroll
      for (int ni = 0; ni < 4; ++ni)
        acc[mi][ni] = __builtin_amdgcn_mfma_f32_16x16x32_bf16(af[mi], bfr[ni], acc[mi][ni], 0, 0, 0);
  };

  stage_load(0);
  stage_write(0);
  __syncthreads();
  int cur = 0;
  for (int t = 0; t < 32; ++t) {
    if (t + 1 < 32) stage_load((t + 1) * 32);
    compute(cur);
    if (t + 1 < 32) stage_write(cur ^ 1);
    __syncthreads();
    cur ^= 1;
  }

  floatx4 acc2[4][2];
  #pragma unroll
  for (int mi = 0; mi < 4; ++mi)
    #pragma unroll
    for (int qi = 0; qi < 2; ++qi)
      acc2[mi][qi] = (floatx4)0.0f;

  float b1v[4];
  #pragma unroll
  for (int ni = 0; ni < 4; ++ni)
    b1v[ni] = b1p[wn * 64 + ni * 16 + (lane & 15)];

  const int w2_q2 = tid & 63;
  const int w2_kq = tid >> 6;

  for (int kc = 0; kc < 4; ++kc) {
    const int kbase = kc * 64;
    float w2reg[16];
    #pragma unroll
    for (int i = 0; i < 8; ++i) {
      const float* pw = W2p + (size_t)(kbase + w2_kq * 8 + i) * H2D + w2_q2 * 2;
      *(float2v*)(&w2reg[2 * i]) = *(const float2v*)(pw);
    }
    #pragma unroll
    for (int dq = 0; dq < 2; ++dq) {
      short8 wv;
      #pragma unroll
      for (int i = 0; i < 8; ++i) wv[i] = bfbits(w2reg[2 * i + dq]);
      const int q = w2_q2 * 2 + dq;
      const int slot = ((q >> 4) * 2 + (w2_kq >> 2)) * 64 + (w2_kq & 3) * 16 + (q & 15);
      *(short8*)(sm + 16384 + slot * 16) = wv;
    }
    if (wn == kc) {
      #pragma unroll
      for (int mi = 0; mi < 4; ++mi) {
        #pragma unroll
        for (int ni = 0; ni < 4; ++ni) {
          const int kl = ni * 16 + (lane & 15);
          const int base = (((wm * 4 + mi) * 2 + (kl >> 5)) * 64 + ((kl >> 3) & 3) * 16) * 16
                           + (kl & 7) * 2;
          #pragma unroll
          for (int r = 0; r < 4; ++r) {
            float v = fmaxf(acc[mi][ni][r] + b1v[ni], 0.0f);
            const int row = (lane >> 4) * 4 + r;
            *(short*)(sm + base + row * 16) = bfbits(v);
          }
        }
      }
    }
    __syncthreads();
    #pragma unroll
    for (int ks = 0; ks < 2; ++ks) {
      short8 hf[4], wf[2];
      #pragma unroll
      for (int mi = 0; mi < 4; ++mi)
        hf[mi] = *(const short8*)(sm + (((wm * 4 + mi) * 2 + ks) * 64 + lane) * 16);
      #pragma unroll
      for (int qi = 0; qi < 2; ++qi)
        wf[qi] = *(const short8*)(sm + 16384 + (((wn * 2 + qi) * 2 + ks) * 64 + lane) * 16);
      #pragma unroll
      for (int mi = 0; mi < 4; ++mi)
        #pragma unroll
        for (int qi = 0; qi < 2; ++qi)
          acc2[mi][qi] = __builtin_amdgcn_mfma_f32_16x16x32_bf16(hf[mi], wf[qi], acc2[mi][qi], 0, 0, 0);
    }
    __syncthreads();
  }

  float lsum[4][4];
  #pragma unroll
  for (int mi = 0; mi < 4; ++mi)
    #pragma unroll
    for (int r = 0; r < 4; ++r) lsum[mi][r] = 0.0f;

  #pragma unroll
  for (int qi = 0; qi < 2; ++qi) {
    const int q = wn * 32 + qi * 16 + (lane & 15);
    const float b2v = b2p[q];
    const float w3v = W3p[q];
    #pragma unroll
    for (int mi = 0; mi < 4; ++mi)
      #pragma unroll
      for (int r = 0; r < 4; ++r) {
        const float h = fmaxf(acc2[mi][qi][r] + b2v, 0.0f);
        lsum[mi][r] += h * w3v;
      }
  }
  #pragma unroll
  for (int mask = 1; mask <= 8; mask <<= 1)
    #pragma unroll
    for (int mi = 0; mi < 4; ++mi)
      #pragma unroll
      for (int r = 0; r < 4; ++r)
        lsum[mi][r] += __shfl_xor(lsum[mi][r], mask, 64);

  float* part = (float*)(sm + 32768);
  if ((lane & 15) == 0) {
    const int g = lane >> 4;
    #pragma unroll
    for (int mi = 0; mi < 4; ++mi)
      #pragma unroll
      for (int r = 0; r < 4; ++r)
        part[wn * 128 + wm * 64 + mi * 16 + g * 4 + r] = lsum[mi][r];
  }
  __syncthreads();
  if (tid < 128) {
    const float x = part[tid] + part[128 + tid] + part[256 + tid] + part[384 + tid] + b3[p];
    const float s = 1.0f / (1.0f + __expf(-x));
    out[(size_t)(m0 + tid) * P_SZ + p] = s;
  }
}

extern "C" void kernel_launch(void* const* d_in, const int* in_sizes, int n_in,
                              void* d_out, int out_size, void* d_ws, size_t ws_size,
                              hipStream_t stream) {
  (void)in_sizes; (void)n_in; (void)out_size;
  const float* feat = (const float*)d_in[0];
  const float* W1   = (const float*)d_in[1];
  const float* b1   = (const float*)d_in[2];
  const float* W2   = (const float*)d_in[3];
  const float* b2   = (const float*)d_in[4];
  const float* W3   = (const float*)d_in[5];
  const float* b3   = (const float*)d_in[6];
  float* out = (float*)d_out;

  if (ws_size >= WS_NEEDED) {
    char* ws = (char*)d_ws;
    hipLaunchKernelGGL(prep_A,  dim3(2048), dim3(256), 0, stream, feat, (short8*)(ws + WS_A_OFF));
    hipLaunchKernelGGL(prep_W1, dim3(8192), dim3(256), 0, stream, W1,   (short8*)(ws + WS_W1_OFF));
    hipLaunchKernelGGL(prep_W2, dim3(1024), dim3(256), 0, stream, W2,   (short8*)(ws + WS_W2_OFF));
    hipLaunchKernelGGL(fused_mlp_v12, dim3(256), dim3(512), 0, stream,
                       (const char*)ws, b1, b2, W3, b3, out);
  } else {
    hipLaunchKernelGGL(fused_mlp_kernel, dim3(2048), dim3(512), 0, stream,
                       feat, W1, b1, W2, b2, W3, b3, out);
  }
}

// Round 13
// 160.300 us; speedup vs baseline: 1.3101x; 1.1967x over previous
//
#include <hip/hip_runtime.h>
#include <hip/hip_bf16.h>

// Problem dims (fixed by reference)
#define B_SZ 4096
#define F_SZ 1024
#define P_SZ 64
#define H1D  256
#define H2D  128

typedef __attribute__((ext_vector_type(8))) short  short8;   // 8 bf16 (4 VGPR) MFMA operand
typedef __attribute__((ext_vector_type(4))) float  floatx4;  // MFMA accumulator
typedef __attribute__((ext_vector_type(2))) float  float2v;
typedef __attribute__((ext_vector_type(4))) float  float4v;

typedef __attribute__((address_space(1))) const void* gas_t;
typedef __attribute__((address_space(3))) void*       las_t;

__device__ __forceinline__ short bfbits(float f) {
  __bf16 h = (__bf16)f;            // RNE, v_cvt_pk_bf16_f32
  return __builtin_bit_cast(short, h);
}

__device__ __forceinline__ void gll16(const void* g, void* l) {
  __builtin_amdgcn_global_load_lds((gas_t)g, (las_t)l, 16, 0, 0);
}

// ---------------- ws layout (bf16, fragment-major, 16x16 shape) ----------------
// A_pre  [0,        8388608): feat  -> [mt128(32)][kt(32)][slot(512)][8]
//        slot = f*64 + kg*16 + row ; value = feat[mt*128+f*16+row][kt*32+kg*8+j]
// W1_pre [8388608, 41943040): W1    -> [p(64)][kt(32)][slot(1024)][8]
//        slot = nf*64 + kg*16 + nr ; value = W1[p][kt*32+kg*8+j][nf*16+nr]
// W2_pre [41943040,46137344): W2    -> [p(64)][kc(4)][slot(1024)][8]
#define WS_A_OFF   0
#define WS_W1_OFF  8388608UL
#define WS_W2_OFF  41943040UL
#define WS_NEEDED  46137344UL

__global__ __launch_bounds__(256) void prep_A(const float* __restrict__ feat,
                                              short8* __restrict__ outv) {
  const int c = blockIdx.x * 256 + threadIdx.x;   // 524288 chunks
  const int row = c & 15, kg = (c >> 4) & 3, f = (c >> 6) & 7, kt = (c >> 9) & 31, mt = c >> 14;
  const float* src = feat + (size_t)(mt * 128 + f * 16 + row) * F_SZ + kt * 32 + kg * 8;
  float4v v0 = *(const float4v*)src;
  float4v v1 = *(const float4v*)(src + 4);
  short8 o;
  #pragma unroll
  for (int j = 0; j < 4; ++j) { o[j] = bfbits(v0[j]); o[4 + j] = bfbits(v1[j]); }
  outv[c] = o;
}

__global__ __launch_bounds__(256) void prep_W1(const float* __restrict__ W1,
                                               short8* __restrict__ outv) {
  const int c = blockIdx.x * 256 + threadIdx.x;   // 2097152 chunks
  const int nr = c & 15, kg = (c >> 4) & 3, nf = (c >> 6) & 15, kt = (c >> 10) & 31, p = c >> 15;
  const float* src = W1 + ((size_t)p * F_SZ + kt * 32 + kg * 8) * H1D + nf * 16 + nr;
  short8 o;
  #pragma unroll
  for (int j = 0; j < 8; ++j) o[j] = bfbits(src[(size_t)j * H1D]);
  outv[c] = o;
}

__global__ __launch_bounds__(256) void prep_W2(const float* __restrict__ W2,
                                               short8* __restrict__ outv) {
  const int c = blockIdx.x * 256 + threadIdx.x;   // 262144 chunks
  const int qr = c & 15, kgl = (c >> 4) & 3, ks = (c >> 6) & 1, qf = (c >> 7) & 7,
            kc = (c >> 10) & 3, p = c >> 12;
  const float* src = W2 + ((size_t)p * H1D + kc * 64 + ks * 32 + kgl * 8) * H2D + qf * 16 + qr;
  short8 o;
  #pragma unroll
  for (int j = 0; j < 8; ++j) o[j] = bfbits(src[(size_t)j * H2D]);
  outv[c] = o;
}

// ---------------- main fused kernel: persistent block, 4 m-tiles, v5 inner loop ----------------
// Grid 256 = 1 block/CU. Block owns one p (and a quarter of its m-tiles: 4 of 16).
// LDS map (163840 bytes = 160KB exactly):
//   L1 bufs  [0, 98304):      3 x 32KB { A c0 8K | A c1 8K | B 16K }
//   W2       [98304, 163840): 64KB, staged ONCE (j==0, t=30/31), resident all 4 m-tiles
//   bufH     overlay [32768, 98304): one k-parity half of h1, A-frag-major (bufs 1+2)
//            -> buf0 stays LIVE across phase 2/3 holding next m-tile's tile 0
//   partials overlay [32768, 36864): f32 [wn(4)][m(256)] (dead bufH, barrier-protected)
// Cross-mt pipelining: next-mt tile0 staged in the free t==31 slot (buf0 dead there);
// prologue for j>0 stages only tile1; vmcnt(4) invariant preserved (oldest-4 = tile0).
#define BAR()   __builtin_amdgcn_s_barrier()
#define VM4()   asm volatile("s_waitcnt vmcnt(4)" ::: "memory")
#define VM0()   asm volatile("s_waitcnt vmcnt(0)" ::: "memory")

__global__ __launch_bounds__(512, 2)
void fused_mlp_v10(const char* __restrict__ ws,
                   const float* __restrict__ b1,
                   const float* __restrict__ b2,
                   const float* __restrict__ W3,
                   const float* __restrict__ b3,
                   float* __restrict__ out) {
  __shared__ __align__(16) char sm[163840];

  const int tid  = threadIdx.x;
  const int lane = tid & 63;
  const int wid  = tid >> 6;
  const int wm   = wid >> 2;   // 0..1 : m-half (128 rows)
  const int wn   = wid & 3;    // 0..3 : n-quarter (64 cols of H1)

  const int bid = blockIdx.x;
  const int wg  = (bid & 7) * 32 + (bid >> 3);    // XCD-chunked, bijective (256%8==0)
  const int p   = wg >> 2;                        // 4 blocks share p (same XCD -> W1 L2-hot)
  const int mq  = wg & 3;                         // m-tile quarter: mt = mq*4 + j

  const char* W1pre = ws + WS_W1_OFF + (size_t)p * 524288;   // per-kt 16KB
  const char* W2pre = ws + WS_W2_OFF + (size_t)p * 65536;    // 64KB

  const int c  = lane & 15;
  const int hi = lane >> 4;

  auto stage = [&](const char* Apre, int ib, int kt) {   // 4 x gll16, 32KB/tile
    char* base = sm + ib * 32768;
    gll16(Apre + (size_t)kt * 8192 + tid * 16,          base + wid * 1024);
    gll16(Apre + 262144 + (size_t)kt * 8192 + tid * 16, base + 8192 + wid * 1024);
    const char* gb = W1pre + (size_t)kt * 16384 + tid * 16;
    gll16(gb,        base + 16384 + wid * 1024);
    gll16(gb + 8192, base + 24576 + wid * 1024);
  };

  for (int j = 0; j < 4; ++j) {
    const int mt = mq * 4 + j;
    const int m0 = mt * 256;
    const char* Apre  = ws + WS_A_OFF + (size_t)(2 * mt) * 262144;  // two 128-row chunks
    const char* ApreN = Apre + 524288;                              // next m-tile (j<3)

    floatx4 acc[8][4];
    #pragma unroll
    for (int i = 0; i < 8; ++i)
      #pragma unroll
      for (int jj = 0; jj < 4; ++jj)
        acc[i][jj] = (floatx4)0.0f;

    // ---- prologue: tile0 (j==0 only; else pre-staged at prev mt's t=31), tile1 ----
    if (j == 0) stage(Apre, 0, 0);
    stage(Apre, 1, 1);
    VM4();   // oldest-4 (tile0) landed; tile1 in flight
    BAR();

    // ---- Layer 1: K = 1024, BK = 32, 3-deep rotation, counted vmcnt(4) ----
    int ibr = 0;
    for (int t = 0; t < 32; ++t) {
      const char* rb = sm + ibr * 32768;
      short8 af[8], bfr[4];
      #pragma unroll
      for (int mi = 0; mi < 8; ++mi)
        af[mi] = *(const short8*)(rb + (wm * 8 + mi) * 1024 + lane * 16);
      #pragma unroll
      for (int ni = 0; ni < 4; ++ni)
        bfr[ni] = *(const short8*)(rb + 16384 + (wn * 4 + ni) * 1024 + lane * 16);

      const int ibs = (ibr == 0) ? 2 : ibr - 1;   // buffer freed at t-1
      if (t < 30) {
        stage(Apre, ibs, t + 2);
      } else if (t == 30) {
        if (j == 0) {   // stage W2 first half into resident region (slots keep vmcnt counts)
          gll16(W2pre + 0 * 8192 + tid * 16, sm + 98304 + 0 * 8192 + wid * 1024);
          gll16(W2pre + 1 * 8192 + tid * 16, sm + 98304 + 1 * 8192 + wid * 1024);
          gll16(W2pre + 2 * 8192 + tid * 16, sm + 98304 + 2 * 8192 + wid * 1024);
          gll16(W2pre + 3 * 8192 + tid * 16, sm + 98304 + 3 * 8192 + wid * 1024);
        }
      } else {          // t == 31: ibs == 0 (buf0 dead) -> prefetch next mt's tile 0
        if (j == 0) {
          gll16(W2pre + 4 * 8192 + tid * 16, sm + 98304 + 4 * 8192 + wid * 1024);
          gll16(W2pre + 5 * 8192 + tid * 16, sm + 98304 + 5 * 8192 + wid * 1024);
          gll16(W2pre + 6 * 8192 + tid * 16, sm + 98304 + 6 * 8192 + wid * 1024);
          gll16(W2pre + 7 * 8192 + tid * 16, sm + 98304 + 7 * 8192 + wid * 1024);
        }
        if (j < 3) stage(ApreN, 0, 0);
      }

      __builtin_amdgcn_s_setprio(1);
      #pragma unroll
      for (int mi = 0; mi < 8; ++mi)
        #pragma unroll
        for (int ni = 0; ni < 4; ++ni)
          acc[mi][ni] = __builtin_amdgcn_mfma_f32_16x16x32_bf16(af[mi], bfr[ni], acc[mi][ni], 0, 0, 0);
      __builtin_amdgcn_s_setprio(0);

      if (t < 31) {
        if (t < 30 || j == 0) VM4();   // tile t+1 landed; newest 4 stay in flight
        else VM0();                    // j>0, t==30: no fresh glls -> drain tile31
        BAR();
      }
      ibr = (ibr == 2) ? 0 : ibr + 1;
    }
    __syncthreads();   // full drain: W2/next-t0 glls landed; bufs 1/2 reusable as bufH

    // ---- Phase 2: layer 2 in two k-parity halves; bufH at [32768,98304) ----
    float b1v[4];
    #pragma unroll
    for (int ni = 0; ni < 4; ++ni)
      b1v[ni] = b1[p * H1D + wn * 64 + ni * 16 + c];

    floatx4 acc2[8][2];
    #pragma unroll
    for (int mi = 0; mi < 8; ++mi)
      #pragma unroll
      for (int qi = 0; qi < 2; ++qi)
        acc2[mi][qi] = (floatx4)0.0f;

    #pragma unroll
    for (int h = 0; h < 2; ++h) {
      // scatter relu(h1+b1) for q-tiles kt2 = 2*wn + h into bufH slot s = wn
      #pragma unroll
      for (int mi = 0; mi < 8; ++mi)
        #pragma unroll
        for (int ii = 0; ii < 2; ++ii) {
          const int ni  = h * 2 + ii;
          const int kg2 = ii * 2 + (c >> 3);
          const int base = 32768 + (wn * 16 + wm * 8 + mi) * 1024 + kg2 * 256 + (c & 7) * 2;
          #pragma unroll
          for (int r = 0; r < 4; ++r) {
            const float v = fmaxf(acc[mi][ni][r] + b1v[ni], 0.0f);
            *(short*)(sm + base + (hi * 4 + r) * 16) = bfbits(v);
          }
        }
      __syncthreads();   // scatter visible

      #pragma unroll
      for (int s = 0; s < 4; ++s) {
        short8 hf[8], wf[2];
        #pragma unroll
        for (int mi = 0; mi < 8; ++mi)
          hf[mi] = *(const short8*)(sm + 32768 + (s * 16 + wm * 8 + mi) * 1024 + lane * 16);
        #pragma unroll
        for (int qi = 0; qi < 2; ++qi)
          wf[qi] = *(const short8*)(sm + 98304 + s * 16384 + (wn * 2 + qi) * 2048
                                    + h * 1024 + lane * 16);
        #pragma unroll
        for (int mi = 0; mi < 8; ++mi)
          #pragma unroll
          for (int qi = 0; qi < 2; ++qi)
            acc2[mi][qi] = __builtin_amdgcn_mfma_f32_16x16x32_bf16(hf[mi], wf[qi], acc2[mi][qi], 0, 0, 0);
      }
      __syncthreads();   // bufH reads done before next half's scatter
    }

    // ---- Layer 3: logits = relu(h2+b2) . W3 + b3 ; sigmoid; transposed store ----
    float lsum[8][4];
    #pragma unroll
    for (int mi = 0; mi < 8; ++mi)
      #pragma unroll
      for (int r = 0; r < 4; ++r) lsum[mi][r] = 0.0f;

    #pragma unroll
    for (int qi = 0; qi < 2; ++qi) {
      const int q = wn * 32 + qi * 16 + c;
      const float b2v = b2[p * H2D + q];
      const float w3v = W3[p * H2D + q];
      #pragma unroll
      for (int mi = 0; mi < 8; ++mi)
        #pragma unroll
        for (int r = 0; r < 4; ++r) {
          const float h2v = fmaxf(acc2[mi][qi][r] + b2v, 0.0f);
          lsum[mi][r] += h2v * w3v;
        }
    }
    #pragma unroll
    for (int mask = 1; mask <= 8; mask <<= 1)
      #pragma unroll
      for (int mi = 0; mi < 8; ++mi)
        #pragma unroll
        for (int r = 0; r < 4; ++r)
          lsum[mi][r] += __shfl_xor(lsum[mi][r], mask, 64);

    float* part = (float*)(sm + 32768);   // dead bufH region; buf0 (next tile0) untouched
    if (c == 0) {
      #pragma unroll
      for (int mi = 0; mi < 8; ++mi)
        #pragma unroll
        for (int r = 0; r < 4; ++r)
          part[wn * 256 + wm * 128 + mi * 16 + hi * 4 + r] = lsum[mi][r];
    }
    __syncthreads();
    if (tid < 256) {
      const float x = part[tid] + part[256 + tid] + part[512 + tid] + part[768 + tid] + b3[p];
      const float s = 1.0f / (1.0f + __expf(-x));
      out[(size_t)(m0 + tid) * P_SZ + p] = s;
    }
    __syncthreads();   // partials reads done before next mt's tile-1 staging reuses buf1
  }
}

// ---------------- fallback (R0 kernel, f32 reg-staged) — used when ws too small ----------------
__global__ __launch_bounds__(512, 2)
void fused_mlp_kernel(const float* __restrict__ feat,
                      const float* __restrict__ W1,
                      const float* __restrict__ b1,
                      const float* __restrict__ W2,
                      const float* __restrict__ b2,
                      const float* __restrict__ W3,
                      const float* __restrict__ b3,
                      float* __restrict__ out) {
  __shared__ __align__(16) char sm[49152];
  const int tid  = threadIdx.x;
  const int lane = tid & 63;
  const int wid  = tid >> 6;
  const int wm   = wid >> 2;
  const int wn   = wid & 3;
  const int bid = blockIdx.x;
  const int wg  = (bid & 7) * 256 + (bid >> 3);
  const int p   = wg >> 5;
  const int mt  = wg & 31;
  const int m0  = mt * 128;

  const float* featm = feat + (size_t)m0 * F_SZ;
  const float* W1p   = W1 + (size_t)p * F_SZ * H1D;
  const float* b1p   = b1 + p * H1D;
  const float* W2p   = W2 + (size_t)p * H1D * H2D;
  const float* b2p   = b2 + p * H2D;
  const float* W3p   = W3 + p * H2D;

  const int a_m  = tid >> 2;
  const int a_kg = tid & 3;
  const int b_n2 = tid & 127;
  const int b_kq = tid >> 7;

  float a_reg[8];
  float b_reg[16];
  floatx4 acc[4][4];
  #pragma unroll
  for (int i = 0; i < 4; ++i)
    #pragma unroll
    for (int j = 0; j < 4; ++j)
      acc[i][j] = (floatx4)0.0f;

  auto stage_load = [&](int k0) {
    const float* pa = featm + a_m * F_SZ + k0 + a_kg * 8;
    *(float4v*)(&a_reg[0]) = *(const float4v*)(pa);
    *(float4v*)(&a_reg[4]) = *(const float4v*)(pa + 4);
    #pragma unroll
    for (int i = 0; i < 8; ++i) {
      const float* pb = W1p + (size_t)(k0 + b_kq * 8 + i) * H1D + b_n2 * 2;
      *(float2v*)(&b_reg[2 * i]) = *(const float2v*)(pb);
    }
  };
  auto stage_write = [&](int cur) {
    short8 av;
    #pragma unroll
    for (int i = 0; i < 8; ++i) av[i] = bfbits(a_reg[i]);
    const int aslot = (a_m >> 4) * 64 + (a_m & 15) + a_kg * 16;
    *(short8*)(sm + cur * 8192 + aslot * 16) = av;
    #pragma unroll
    for (int dn = 0; dn < 2; ++dn) {
      short8 bv;
      #pragma unroll
      for (int i = 0; i < 8; ++i) bv[i] = bfbits(b_reg[2 * i + dn]);
      const int n = b_n2 * 2 + dn;
      const int bslot = (n >> 4) * 64 + (n & 15) + b_kq * 16;
      *(short8*)(sm + 16384 + cur * 16384 + bslot * 16) = bv;
    }
  };
  auto compute = [&](int cur) {
    short8 af[4], bfr[4];
    #pragma unroll
    for (int mi = 0; mi < 4; ++mi)
      af[mi] = *(const short8*)(sm + cur * 8192 + ((wm * 4 + mi) * 64 + lane) * 16);
    #pragma unroll
    for (int ni = 0; ni < 4; ++ni)
      bfr[ni] = *(const short8*)(sm + 16384 + cur * 16384 + ((wn * 4 + ni) * 64 + lane) * 16);
    #pragma unroll
    for (int mi = 0; mi < 4; ++mi)
      #pragma unroll
      for (int ni = 0; ni < 4; ++ni)
        acc[mi][ni] = __builtin_amdgcn_mfma_f32_16x16x32_bf16(af[mi], bfr[ni], acc[mi][ni], 0, 0, 0);
  };

  stage_load(0);
  stage_write(0);
  __syncthreads();
  int cur = 0;
  for (int t = 0; t < 32; ++t) {
    if (t + 1 < 32) stage_load((t + 1) * 32);
    compute(cur);
    if (t + 1 < 32) stage_write(cur ^ 1);
    __syncthreads();
    cur ^= 1;
  }

  floatx4 acc2[4][2];
  #pragma unroll
  for (int mi = 0; mi < 4; ++mi)
    #pragma unroll
    for (int qi = 0; qi < 2; ++qi)
      acc2[mi][qi] = (floatx4)0.0f;

  float b1v[4];
  #pragma unroll
  for (int ni = 0; ni < 4; ++ni)
    b1v[ni] = b1p[wn * 64 + ni * 16 + (lane & 15)];

  const int w2_q2 = tid & 63;
  const int w2_kq = tid >> 6;

  for (int kc = 0; kc < 4; ++kc) {
    const int kbase = kc * 64;
    float w2reg[16];
    #pragma unroll
    for (int i = 0; i < 8; ++i) {
      const float* pw = W2p + (size_t)(kbase + w2_kq * 8 + i) * H2D + w2_q2 * 2;
      *(float2v*)(&w2reg[2 * i]) = *(const float2v*)(pw);
    }
    #pragma unroll
    for (int dq = 0; dq < 2; ++dq) {
      short8 wv;
      #pragma unroll
      for (int i = 0; i < 8; ++i) wv[i] = bfbits(w2reg[2 * i + dq]);
      const int q = w2_q2 * 2 + dq;
      const int slot = ((q >> 4) * 2 + (w2_kq >> 2)) * 64 + (w2_kq & 3) * 16 + (q & 15);
      *(short8*)(sm + 16384 + slot * 16) = wv;
    }
    if (wn == kc) {
      #pragma unroll
      for (int mi = 0; mi < 4; ++mi) {
        #pragma unroll
        for (int ni = 0; ni < 4; ++ni) {
          const int kl = ni * 16 + (lane & 15);
          const int base = (((wm * 4 + mi) * 2 + (kl >> 5)) * 64 + ((kl >> 3) & 3) * 16) * 16
                           + (kl & 7) * 2;
          #pragma unroll
          for (int r = 0; r < 4; ++r) {
            float v = fmaxf(acc[mi][ni][r] + b1v[ni], 0.0f);
            const int row = (lane >> 4) * 4 + r;
            *(short*)(sm + base + row * 16) = bfbits(v);
          }
        }
      }
    }
    __syncthreads();
    #pragma unroll
    for (int ks = 0; ks < 2; ++ks) {
      short8 hf[4], wf[2];
      #pragma unroll
      for (int mi = 0; mi < 4; ++mi)
        hf[mi] = *(const short8*)(sm + (((wm * 4 + mi) * 2 + ks) * 64 + lane) * 16);
      #pragma unroll
      for (int qi = 0; qi < 2; ++qi)
        wf[qi] = *(const short8*)(sm + 16384 + (((wn * 2 + qi) * 2 + ks) * 64 + lane) * 16);
      #pragma unroll
      for (int mi = 0; mi < 4; ++mi)
        #pragma unroll
        for (int qi = 0; qi < 2; ++qi)
          acc2[mi][qi] = __builtin_amdgcn_mfma_f32_16x16x32_bf16(hf[mi], wf[qi], acc2[mi][qi], 0, 0, 0);
    }
    __syncthreads();
  }

  float lsum[4][4];
  #pragma unroll
  for (int mi = 0; mi < 4; ++mi)
    #pragma unroll
    for (int r = 0; r < 4; ++r) lsum[mi][r] = 0.0f;

  #pragma unroll
  for (int qi = 0; qi < 2; ++qi) {
    const int q = wn * 32 + qi * 16 + (lane & 15);
    const float b2v = b2p[q];
    const float w3v = W3p[q];
    #pragma unroll
    for (int mi = 0; mi < 4; ++mi)
      #pragma unroll
      for (int r = 0; r < 4; ++r) {
        const float h = fmaxf(acc2[mi][qi][r] + b2v, 0.0f);
        lsum[mi][r] += h * w3v;
      }
  }
  #pragma unroll
  for (int mask = 1; mask <= 8; mask <<= 1)
    #pragma unroll
    for (int mi = 0; mi < 4; ++mi)
      #pragma unroll
      for (int r = 0; r < 4; ++r)
        lsum[mi][r] += __shfl_xor(lsum[mi][r], mask, 64);

  float* part = (float*)(sm + 32768);
  if ((lane & 15) == 0) {
    const int g = lane >> 4;
    #pragma unroll
    for (int mi = 0; mi < 4; ++mi)
      #pragma unroll
      for (int r = 0; r < 4; ++r)
        part[wn * 128 + wm * 64 + mi * 16 + g * 4 + r] = lsum[mi][r];
  }
  __syncthreads();
  if (tid < 128) {
    const float x = part[tid] + part[128 + tid] + part[256 + tid] + part[384 + tid] + b3[p];
    const float s = 1.0f / (1.0f + __expf(-x));
    out[(size_t)(m0 + tid) * P_SZ + p] = s;
  }
}

extern "C" void kernel_launch(void* const* d_in, const int* in_sizes, int n_in,
                              void* d_out, int out_size, void* d_ws, size_t ws_size,
                              hipStream_t stream) {
  (void)in_sizes; (void)n_in; (void)out_size;
  const float* feat = (const float*)d_in[0];
  const float* W1   = (const float*)d_in[1];
  const float* b1   = (const float*)d_in[2];
  const float* W2   = (const float*)d_in[3];
  const float* b2   = (const float*)d_in[4];
  const float* W3   = (const float*)d_in[5];
  const float* b3   = (const float*)d_in[6];
  float* out = (float*)d_out;

  if (ws_size >= WS_NEEDED) {
    char* ws = (char*)d_ws;
    hipLaunchKernelGGL(prep_A,  dim3(2048), dim3(256), 0, stream, feat, (short8*)(ws + WS_A_OFF));
    hipLaunchKernelGGL(prep_W1, dim3(8192), dim3(256), 0, stream, W1,   (short8*)(ws + WS_W1_OFF));
    hipLaunchKernelGGL(prep_W2, dim3(1024), dim3(256), 0, stream, W2,   (short8*)(ws + WS_W2_OFF));
    hipLaunchKernelGGL(fused_mlp_v10, dim3(256), dim3(512), 0, stream,
                       (const char*)ws, b1, b2, W3, b3, out);
  } else {
    hipLaunchKernelGGL(fused_mlp_kernel, dim3(2048), dim3(512), 0, stream,
                       feat, W1, b1, W2, b2, W3, b3, out);
  }
}